// Round 5
// baseline (188.700 us; speedup 1.0000x reference)
//
#include <hip/hip_runtime.h>
#include <hip/hip_bf16.h>

#define NODES 8192
#define INF_ 256
#define OUTF 128
#define LRALPHA 0.02f

typedef __bf16 bf16;
typedef bf16 bf16x8 __attribute__((ext_vector_type(8)));
typedef float f32x4 __attribute__((ext_vector_type(4)));
typedef float f32x16 __attribute__((ext_vector_type(16)));
typedef int i32x4 __attribute__((ext_vector_type(4)));

// ---------------- Kernel 1: Wh = x@W1 + b1 (f32) -> WhbT(bf16) + factored exp arrays ----
__global__ __launch_bounds__(256) void gat_prep_r5(
    const float* __restrict__ x, const float* __restrict__ W1,
    const float* __restrict__ b1, const float* __restrict__ a,
    const float* __restrict__ b_att,
    bf16* __restrict__ WhbT, float* __restrict__ E1,
    float* __restrict__ E2, float* __restrict__ F1, float* __restrict__ F2)
{
    __shared__ float xsT[64][36];    // [k][row], padded
    __shared__ float ws1[64][132];   // [k][col], padded
    __shared__ float wh[32][128];    // Wh tile f32

    const int t = threadIdx.x;
    const int rbase = blockIdx.x * 32;
    const int tr = t >> 5;   // 0..7  -> rows tr*4..+3
    const int tc = t & 31;   // 0..31 -> cols tc*4..+3

    f32x4 acc[4];
    f32x4 bias = *(const f32x4*)&b1[tc * 4];
#pragma unroll
    for (int i = 0; i < 4; ++i) acc[i] = bias;

    for (int kt = 0; kt < 4; ++kt) {
        const int kb = kt * 64;
        {   // stage x tile transposed: xsT[k][r] = x[rbase+r][kb+k]
            int r = t >> 3;            // 0..31
            int kq = (t & 7) * 8;      // 0..56
            f32x4 v0 = *(const f32x4*)&x[(size_t)(rbase + r) * INF_ + kb + kq];
            f32x4 v1 = *(const f32x4*)&x[(size_t)(rbase + r) * INF_ + kb + kq + 4];
#pragma unroll
            for (int i = 0; i < 4; ++i) xsT[kq + i][r] = v0[i];
#pragma unroll
            for (int i = 0; i < 4; ++i) xsT[kq + 4 + i][r] = v1[i];
        }
        {   // stage W1 tile: ws1[k][c] = W1[kb+k][c]
            int kr = t >> 2;           // 0..63
            int cq = (t & 3) * 32;
#pragma unroll
            for (int i = 0; i < 8; ++i) {
                f32x4 v = *(const f32x4*)&W1[(size_t)(kb + kr) * OUTF + cq + i * 4];
                *(f32x4*)&ws1[kr][cq + i * 4] = v;
            }
        }
        __syncthreads();
        for (int kk = 0; kk < 64; ++kk) {
            f32x4 xa = *(const f32x4*)&xsT[kk][tr * 4];
            f32x4 wb = *(const f32x4*)&ws1[kk][tc * 4];
#pragma unroll
            for (int i = 0; i < 4; ++i)
#pragma unroll
                for (int j = 0; j < 4; ++j)
                    acc[i][j] += xa[i] * wb[j];
        }
        __syncthreads();
    }

#pragma unroll
    for (int i = 0; i < 4; ++i)
        *(f32x4*)&wh[tr * 4 + i][tc * 4] = acc[i];
    __syncthreads();

    if (t < 32) {
        float s1 = 0.f, s2 = 0.f;
        for (int c = 0; c < OUTF; ++c) {
            float v = wh[t][c];
            s1 += v * a[c];
            s2 += v * a[OUTF + c];
        }
        float fsv = s1 + b_att[0];
        int r = rbase + t;
        E1[r] = expf(fsv);
        E2[r] = expf(LRALPHA * fsv);
        F1[r] = expf(s2);
        F2[r] = expf(LRALPHA * s2);
    }

    {   // WhbT[c][node] = bf16(Wh[node][c])
        int c = t >> 1;
        int rr = (t & 1) * 16;
        bf16x8 b0, b1v;
#pragma unroll
        for (int i = 0; i < 8; ++i) b0[i] = (bf16)wh[rr + i][c];
#pragma unroll
        for (int i = 0; i < 8; ++i) b1v[i] = (bf16)wh[rr + 8 + i][c];
        *(bf16x8*)&WhbT[(size_t)c * NODES + rbase + rr] = b0;
        *(bf16x8*)&WhbT[(size_t)c * NODES + rbase + rr + 8] = b1v;
    }
}

// ---------------- Kernel 2: barrier-free transposed-MFMA attention ----------------
// outT[c][r] = sum_j WhbT[c][j] * w[r][j].  B-fragment (col=lane&31 -> r,
// k=(lane>>5)*8+e -> j) == the 8 weights lane computes locally. No LDS w-tile,
// no barriers in the main loop -> loads pipeline freely across iterations.
// 16 waves = 8 col-strips (1024 cols) x 2 output halves (64 cols).
#define DENRED_OFF 0
#define TAB_OFF    1024
#define ZONE_OFF   1024         // zones alias tables (dead after main loop)
#define SMEM2_SIZE (1024 + 65536)

__global__ __launch_bounds__(1024, 4) void gat_attn_r5(
    const int* __restrict__ adj,
    const bf16* __restrict__ WhbT,
    const float* __restrict__ E1, const float* __restrict__ E2,
    const float* __restrict__ F1, const float* __restrict__ F2,
    float* __restrict__ out)
{
    extern __shared__ char smem[];
    float* denred = (float*)(smem + DENRED_OFF);       // [8][32]
    float* F1t = (float*)(smem + TAB_OFF);             // 8192 f32
    float* F2t = (float*)(smem + TAB_OFF + 32768);     // 8192 f32
    char* zones = smem + ZONE_OFF;                     // 8 slots x 8KB

    const int tid = threadIdx.x;
    const int lane = tid & 63;
    const int wv = tid >> 6;       // 0..15
    const int strip = wv >> 1;     // 0..7 : 1024-col strip
    const int mh = wv & 1;         // 0..1 : output col half
    const int rbase = blockIdx.x * 32;
    const int r = lane & 31;
    const int ag = lane >> 5;      // k half

    {   // stage F1/F2 tables (8 floats per thread per table)
        int i = tid * 8;
        *(f32x4*)&F1t[i]     = *(const f32x4*)&F1[i];
        *(f32x4*)&F1t[i + 4] = *(const f32x4*)&F1[i + 4];
        *(f32x4*)&F2t[i]     = *(const f32x4*)&F2[i];
        *(f32x4*)&F2t[i + 4] = *(const f32x4*)&F2[i + 4];
    }

    const float e1v = E1[rbase + r];
    const float e2v = E2[rbase + r];
    const size_t adj_row = (size_t)(rbase + r) * NODES;
    const int j00 = strip * 1024;
    const size_t wrow0 = (size_t)(r + 64 * mh) * NODES;        // acc0 rows
    const size_t wrow1 = wrow0 + (size_t)32 * NODES;           // acc1 rows

    f32x16 acc0, acc1;
#pragma unroll
    for (int i = 0; i < 16; ++i) { acc0[i] = 0.f; acc1[i] = 0.f; }
    float den = 0.f;

    __syncthreads();   // tables staged

    // prologue: adj(s=0), adj(s=1), whb(s=0)
    i32x4 ca0 = *(const i32x4*)&adj[adj_row + j00 + ag * 8];
    i32x4 ca1 = *(const i32x4*)&adj[adj_row + j00 + ag * 8 + 4];
    i32x4 na0 = *(const i32x4*)&adj[adj_row + j00 + 16 + ag * 8];
    i32x4 na1 = *(const i32x4*)&adj[adj_row + j00 + 16 + ag * 8 + 4];
    bf16x8 wc0 = *(const bf16x8*)&WhbT[wrow0 + j00 + ag * 8];
    bf16x8 wc1 = *(const bf16x8*)&WhbT[wrow1 + j00 + ag * 8];

#pragma unroll 4
    for (int s = 0; s < 64; ++s) {
        const int jl = j00 + s * 16 + ag * 8;
        // prefetch adj(s+2), whb(s+1) — consumed 2 / 1 iterations later
        const int sc = (s + 2 <= 63) ? (s + 2) : 63;
        const int sw = (s + 1 <= 63) ? (s + 1) : 63;
        i32x4 fa0 = *(const i32x4*)&adj[adj_row + j00 + sc * 16 + ag * 8];
        i32x4 fa1 = *(const i32x4*)&adj[adj_row + j00 + sc * 16 + ag * 8 + 4];
        bf16x8 wn0 = *(const bf16x8*)&WhbT[wrow0 + j00 + sw * 16 + ag * 8];
        bf16x8 wn1 = *(const bf16x8*)&WhbT[wrow1 + j00 + sw * 16 + ag * 8];

        // LDS broadcast tables for this lane's 8 columns
        f32x4 g1a = *(const f32x4*)&F1t[jl];
        f32x4 g1b = *(const f32x4*)&F1t[jl + 4];
        f32x4 g2a = *(const f32x4*)&F2t[jl];
        f32x4 g2b = *(const f32x4*)&F2t[jl + 4];

        // 8 weights (this lane's B-fragment), den in f32
        bf16x8 wb;
#pragma unroll
        for (int jj = 0; jj < 4; ++jj) {
            float tv = e1v * g1a[jj];                 // e^s ; s>0 <=> tv>1
            float w = tv > 1.f ? tv : e2v * g2a[jj];
            w = ca0[jj] ? w : 0.f;
            den += w;
            wb[jj] = (bf16)w;
        }
#pragma unroll
        for (int jj = 0; jj < 4; ++jj) {
            float tv = e1v * g1b[jj];
            float w = tv > 1.f ? tv : e2v * g2b[jj];
            w = ca1[jj] ? w : 0.f;
            den += w;
            wb[4 + jj] = (bf16)w;
        }

        acc0 = __builtin_amdgcn_mfma_f32_32x32x16_bf16(wc0, wb, acc0, 0, 0, 0);
        acc1 = __builtin_amdgcn_mfma_f32_32x32x16_bf16(wc1, wb, acc1, 0, 0, 0);

        ca0 = na0; ca1 = na1; na0 = fa0; na1 = fa1;
        wc0 = wn0; wc1 = wn1;
    }

    // den: lanes l and l^32 share row r
    den += __shfl_xor(den, 32);

    __syncthreads();   // all waves done; tables dead, zones live
    if (mh == 0 && lane < 32) denred[strip * 32 + lane] = den;

    // cascade reduction over 8 strips: 8 -> 4 -> 2 -> 1
    auto dump = [&](int slot) {
        float* z = (float*)(zones + (size_t)slot * 8192) + lane * 32;
        *(f32x16*)z = acc0;
        *(f32x16*)(z + 16) = acc1;
    };
    auto take = [&](int slot) {
        const float* z = (const float*)(zones + (size_t)slot * 8192) + lane * 32;
        f32x16 v0 = *(const f32x16*)z;
        f32x16 v1 = *(const f32x16*)(z + 16);
#pragma unroll
        for (int i = 0; i < 16; ++i) { acc0[i] += v0[i]; acc1[i] += v1[i]; }
    };

    if (strip >= 4) dump((strip - 4) * 2 + mh);
    __syncthreads();
    if (strip < 4) take(strip * 2 + mh);
    __syncthreads();
    if (strip == 2 || strip == 3) dump((strip - 2) * 2 + mh);
    __syncthreads();
    if (strip < 2) take(strip * 2 + mh);
    __syncthreads();
    if (strip == 1) dump(mh);
    __syncthreads();

    if (strip == 0) {
        take(mh);
        float ds = 0.f;
#pragma unroll
        for (int w = 0; w < 8; ++w) ds += denred[w * 32 + r];
        const float inv = 1.f / ds;
        // C/D mapping: D col = lane&31 = r, D row = (rg&3)+8*(rg>>2)+4*ag = c
#pragma unroll
        for (int u = 0; u < 4; ++u) {
            f32x4 o0, o1;
#pragma unroll
            for (int e = 0; e < 4; ++e) {
                float v0 = acc0[4 * u + e] * inv;
                float v1 = acc1[4 * u + e] * inv;
                o0[e] = v0 > 0.f ? v0 : expm1f(v0);
                o1[e] = v1 > 0.f ? v1 : expm1f(v1);
            }
            const int cbase = 8 * u + 4 * ag;
            *(f32x4*)&out[(size_t)(rbase + r) * OUTF + 64 * mh + cbase] = o0;
            *(f32x4*)&out[(size_t)(rbase + r) * OUTF + 64 * mh + 32 + cbase] = o1;
        }
    }
}

extern "C" void kernel_launch(void* const* d_in, const int* in_sizes, int n_in,
                              void* d_out, int out_size, void* d_ws, size_t ws_size,
                              hipStream_t stream) {
    const float* x     = (const float*)d_in[0];
    const int*   adj   = (const int*)d_in[1];
    const float* W1    = (const float*)d_in[2];
    const float* b1    = (const float*)d_in[3];
    const float* a     = (const float*)d_in[4];
    const float* b_att = (const float*)d_in[5];
    float* out = (float*)d_out;

    char* ws = (char*)d_ws;
    bf16* WhbT = (bf16*)ws;                                   // 2 MB
    float* E1 = (float*)(ws + (size_t)2 * 1024 * 1024);
    float* E2 = E1 + NODES;
    float* F1 = E2 + NODES;
    float* F2 = F1 + NODES;

    hipLaunchKernelGGL(gat_prep_r5, dim3(NODES / 32), dim3(256), 0, stream,
                       x, W1, b1, a, b_att, WhbT, E1, E2, F1, F2);

    hipLaunchKernelGGL(gat_attn_r5, dim3(NODES / 32), dim3(1024), SMEM2_SIZE, stream,
                       adj, WhbT, E1, E2, F1, F2, out);
}

// Round 6
// 126.258 us; speedup vs baseline: 1.4946x; 1.4946x over previous
//
#include <hip/hip_runtime.h>
#include <hip/hip_bf16.h>

#define NODES 8192
#define INF_ 256
#define OUTF 128
#define LRALPHA 0.02f

typedef __bf16 bf16;
typedef bf16 bf16x8 __attribute__((ext_vector_type(8)));
typedef float f32x4 __attribute__((ext_vector_type(4)));
typedef float f32x16 __attribute__((ext_vector_type(16)));
typedef int i32x4 __attribute__((ext_vector_type(4)));

// ---------------- Kernel 0: bitpack adj (256MB int32 -> 8MB bitmask) ----------------
// Pure streaming: wave reads 512 consecutive ints (8 coalesced dword loads), 8 ballots,
// lanes 0..7 write 8 consecutive u64. No dependency chains -> fillBuffer-class BW.
__global__ __launch_bounds__(256) void gat_pack_r6(
    const int* __restrict__ adj, unsigned long long* __restrict__ mask)
{
    const int lane = threadIdx.x & 63;
    const size_t W = ((size_t)blockIdx.x * 256 + threadIdx.x) >> 6;
    const size_t base = W * 512;
    int v[8];
#pragma unroll
    for (int e = 0; e < 8; ++e) v[e] = adj[base + (size_t)e * 64 + lane];
#pragma unroll
    for (int e = 0; e < 8; ++e) {
        unsigned long long b = __ballot(v[e] != 0);
        if (lane == e) mask[W * 8 + e] = b;
    }
}

// ---------------- Kernel 1: Wh = x@W1 + b1 -> WhbF (MFMA fragment order) + exp arrays ----
// WhbF fragment f = (jblk*4 + fb): 64 lanes x 16B contiguous; lane holds
// Wh[jblk*16 + (lane>>5)*8 + e][fb*32 + (lane&31)], e=0..7.
__global__ __launch_bounds__(256) void gat_prep_r6(
    const float* __restrict__ x, const float* __restrict__ W1,
    const float* __restrict__ b1, const float* __restrict__ a,
    const float* __restrict__ b_att,
    bf16* __restrict__ WhbF, float* __restrict__ E1,
    float* __restrict__ E2, float* __restrict__ F1, float* __restrict__ F2)
{
    __shared__ float xsT[64][36];    // [k][row], padded
    __shared__ float ws1[64][132];   // [k][col], padded
    __shared__ float wh[32][128];    // Wh tile f32

    const int t = threadIdx.x;
    const int rbase = blockIdx.x * 32;
    const int tr = t >> 5;   // 0..7  -> rows tr*4..+3
    const int tc = t & 31;   // 0..31 -> cols tc*4..+3

    f32x4 acc[4];
    f32x4 bias = *(const f32x4*)&b1[tc * 4];
#pragma unroll
    for (int i = 0; i < 4; ++i) acc[i] = bias;

    for (int kt = 0; kt < 4; ++kt) {
        const int kb = kt * 64;
        {   // stage x tile transposed: xsT[k][r] = x[rbase+r][kb+k]
            int r = t >> 3;            // 0..31
            int kq = (t & 7) * 8;      // 0..56
            f32x4 v0 = *(const f32x4*)&x[(size_t)(rbase + r) * INF_ + kb + kq];
            f32x4 v1 = *(const f32x4*)&x[(size_t)(rbase + r) * INF_ + kb + kq + 4];
#pragma unroll
            for (int i = 0; i < 4; ++i) xsT[kq + i][r] = v0[i];
#pragma unroll
            for (int i = 0; i < 4; ++i) xsT[kq + 4 + i][r] = v1[i];
        }
        {   // stage W1 tile: ws1[k][c] = W1[kb+k][c]
            int kr = t >> 2;           // 0..63
            int cq = (t & 3) * 32;
#pragma unroll
            for (int i = 0; i < 8; ++i) {
                f32x4 v = *(const f32x4*)&W1[(size_t)(kb + kr) * OUTF + cq + i * 4];
                *(f32x4*)&ws1[kr][cq + i * 4] = v;
            }
        }
        __syncthreads();
        for (int kk = 0; kk < 64; ++kk) {
            f32x4 xa = *(const f32x4*)&xsT[kk][tr * 4];
            f32x4 wb = *(const f32x4*)&ws1[kk][tc * 4];
#pragma unroll
            for (int i = 0; i < 4; ++i)
#pragma unroll
                for (int j = 0; j < 4; ++j)
                    acc[i][j] += xa[i] * wb[j];
        }
        __syncthreads();
    }

#pragma unroll
    for (int i = 0; i < 4; ++i)
        *(f32x4*)&wh[tr * 4 + i][tc * 4] = acc[i];
    __syncthreads();

    if (t < 32) {
        float s1 = 0.f, s2 = 0.f;
        for (int c = 0; c < OUTF; ++c) {
            float v = wh[t][c];
            s1 += v * a[c];
            s2 += v * a[OUTF + c];
        }
        float fsv = s1 + b_att[0];
        int r = rbase + t;
        E1[r] = expf(fsv);
        E2[r] = expf(LRALPHA * fsv);
        F1[r] = expf(s2);
        F2[r] = expf(LRALPHA * s2);
    }

    {   // WhbF fragment writes: thread t -> (kb, fb, c), two lane-halves h
        const int kb = t >> 7;          // 0..1
        const int fb = (t >> 5) & 3;    // 0..3
        const int c  = t & 31;          // feat within fb
        const size_t jblk = (size_t)blockIdx.x * 2 + kb;
#pragma unroll
        for (int h = 0; h < 2; ++h) {
            const int lane = c + h * 32;
            bf16x8 v;
#pragma unroll
            for (int e = 0; e < 8; ++e)
                v[e] = (bf16)wh[kb * 16 + h * 8 + e][fb * 32 + c];
            *(bf16x8*)&WhbF[((jblk * 4 + fb) * 64 + lane) * 8] = v;
        }
    }
}

// ---------------- Kernel 2: scatter-free masked softmax + PV (bf16 MFMA) + elu ----------
// 16 waves = 16 K-strips of 512 cols. Each wave: full 32x128 output partial (acc 64 VGPR),
// weights computed once, adj from bitmask (16 words/lane, loaded once per strip),
// WhbF fragment loads 1KB-contiguous, F1/F2 LDS broadcast tables. log2 cascade epilogue.
// LDS: [0,2048) denred[16][32]; [2048,67584) F tables (64KB, dead after main loop);
//      [2048,133120) 8 cascade zones x 16KB (alias tables).
#define DENRED_OFF 0
#define TAB_OFF    2048
#define ZONE_OFF   2048
#define SMEM2_SIZE 133120

__global__ __launch_bounds__(1024, 4) void gat_attn_r6(
    const unsigned int* __restrict__ m32,
    const bf16* __restrict__ WhbF,
    const float* __restrict__ E1, const float* __restrict__ E2,
    const float* __restrict__ F1, const float* __restrict__ F2,
    float* __restrict__ out)
{
    extern __shared__ char smem[];
    float* denred = (float*)(smem + DENRED_OFF);
    float* F1t = (float*)(smem + TAB_OFF);             // 8192 f32
    float* F2t = (float*)(smem + TAB_OFF + 32768);     // 8192 f32

    const int tid = threadIdx.x;
    const int lane = tid & 63;
    const int wv = tid >> 6;        // 0..15 : K-strip
    const int rbase = blockIdx.x * 32;
    const int r = lane & 31;
    const int ag = lane >> 5;
    const int agsh = ag * 8;

    {   // stage F1/F2 tables (8 floats per thread per table)
        int i = tid * 8;
        *(f32x4*)&F1t[i]     = *(const f32x4*)&F1[i];
        *(f32x4*)&F1t[i + 4] = *(const f32x4*)&F1[i + 4];
        *(f32x4*)&F2t[i]     = *(const f32x4*)&F2[i];
        *(f32x4*)&F2t[i + 4] = *(const f32x4*)&F2[i + 4];
    }

    const float e1v = E1[rbase + r];
    const float e2v = E2[rbase + r];
    const int j0 = wv * 512;
    const size_t mrow = (size_t)(rbase + r) * 256 + wv * 16;

    f32x16 acc0, acc1, acc2, acc3;
#pragma unroll
    for (int i = 0; i < 16; ++i) { acc0[i] = 0.f; acc1[i] = 0.f; acc2[i] = 0.f; acc3[i] = 0.f; }
    float den = 0.f;

    __syncthreads();   // tables staged

    // 16 iterations of 16 cols, mask words ma/mb (static element access after unroll)
    auto run16 = [&](i32x4 ma, i32x4 mb, int sbase) {
#pragma unroll
        for (int s2 = 0; s2 < 16; ++s2) {
            const int s = sbase + s2;
            const size_t fbase = ((size_t)(wv * 32 + s) * 4) * 512 + lane * 8;
            bf16x8 wc0 = *(const bf16x8*)&WhbF[fbase];
            bf16x8 wc1 = *(const bf16x8*)&WhbF[fbase + 512];
            bf16x8 wc2 = *(const bf16x8*)&WhbF[fbase + 1024];
            bf16x8 wc3 = *(const bf16x8*)&WhbF[fbase + 1536];

            const int jl = j0 + s * 16 + agsh;
            f32x4 g1a = *(const f32x4*)&F1t[jl];
            f32x4 g1b = *(const f32x4*)&F1t[jl + 4];
            f32x4 g2a = *(const f32x4*)&F2t[jl];
            f32x4 g2b = *(const f32x4*)&F2t[jl + 4];

            const unsigned int word =
                ((s2 >> 1) < 4) ? (unsigned int)ma[(s2 >> 1) & 3]
                                : (unsigned int)mb[(s2 >> 1) & 3];
            const unsigned int b8 = word >> (((s2 & 1) << 4) + agsh);

            bf16x8 wb;
#pragma unroll
            for (int jj = 0; jj < 4; ++jj) {
                float tv = e1v * g1a[jj];                 // e^s ; s>0 <=> tv>1
                float w = tv > 1.f ? tv : e2v * g2a[jj];
                w = (b8 & (1u << jj)) ? w : 0.f;
                den += w;
                wb[jj] = (bf16)w;
            }
#pragma unroll
            for (int jj = 0; jj < 4; ++jj) {
                float tv = e1v * g1b[jj];
                float w = tv > 1.f ? tv : e2v * g2b[jj];
                w = (b8 & (16u << jj)) ? w : 0.f;
                den += w;
                wb[4 + jj] = (bf16)w;
            }

            acc0 = __builtin_amdgcn_mfma_f32_32x32x16_bf16(wc0, wb, acc0, 0, 0, 0);
            acc1 = __builtin_amdgcn_mfma_f32_32x32x16_bf16(wc1, wb, acc1, 0, 0, 0);
            acc2 = __builtin_amdgcn_mfma_f32_32x32x16_bf16(wc2, wb, acc2, 0, 0, 0);
            acc3 = __builtin_amdgcn_mfma_f32_32x32x16_bf16(wc3, wb, acc3, 0, 0, 0);
        }
    };

    {
        i32x4 mA = *(const i32x4*)&m32[mrow];
        i32x4 mB = *(const i32x4*)&m32[mrow + 4];
        run16(mA, mB, 0);
    }
    {
        i32x4 mC = *(const i32x4*)&m32[mrow + 8];
        i32x4 mD = *(const i32x4*)&m32[mrow + 12];
        run16(mC, mD, 16);
    }

    den += __shfl_xor(den, 32);

    __syncthreads();   // main loop done everywhere; tables dead, zones live
    if (lane < 32) denred[wv * 32 + r] = den;

    auto dump = [&](int slot) {
        float* z = (float*)(smem + ZONE_OFF + (size_t)slot * 16384) + lane * 64;
        *(f32x16*)(z)      = acc0;
        *(f32x16*)(z + 16) = acc1;
        *(f32x16*)(z + 32) = acc2;
        *(f32x16*)(z + 48) = acc3;
    };
    auto take = [&](int slot) {
        const float* z = (const float*)(smem + ZONE_OFF + (size_t)slot * 16384) + lane * 64;
        f32x16 v0 = *(const f32x16*)(z);
        f32x16 v1 = *(const f32x16*)(z + 16);
        f32x16 v2 = *(const f32x16*)(z + 32);
        f32x16 v3 = *(const f32x16*)(z + 48);
#pragma unroll
        for (int i = 0; i < 16; ++i) {
            acc0[i] += v0[i]; acc1[i] += v1[i]; acc2[i] += v2[i]; acc3[i] += v3[i];
        }
    };

    if (wv >= 8) dump(wv - 8);
    __syncthreads();
    if (wv < 8) take(wv);
    __syncthreads();
    if (wv >= 4 && wv < 8) dump(wv - 4);
    __syncthreads();
    if (wv < 4) take(wv);
    __syncthreads();
    if (wv == 2 || wv == 3) dump(wv - 2);
    __syncthreads();
    if (wv < 2) take(wv);
    __syncthreads();
    if (wv == 1) dump(0);
    __syncthreads();

    if (wv == 0) {
        take(0);
        float ds = 0.f;
#pragma unroll
        for (int w = 0; w < 16; ++w) ds += denred[w * 32 + r];
        const float inv = 1.f / ds;
        const size_t orow = (size_t)(rbase + r) * OUTF;
#pragma unroll
        for (int fb = 0; fb < 4; ++fb) {
            const f32x16* A = (fb == 0) ? &acc0 : (fb == 1) ? &acc1 : (fb == 2) ? &acc2 : &acc3;
#pragma unroll
            for (int u = 0; u < 4; ++u) {
                f32x4 o;
#pragma unroll
                for (int e = 0; e < 4; ++e) {
                    float v = (*A)[4 * u + e] * inv;
                    o[e] = v > 0.f ? v : expm1f(v);
                }
                *(f32x4*)&out[orow + fb * 32 + 8 * u + 4 * ag] = o;
            }
        }
    }
}

extern "C" void kernel_launch(void* const* d_in, const int* in_sizes, int n_in,
                              void* d_out, int out_size, void* d_ws, size_t ws_size,
                              hipStream_t stream) {
    const float* x     = (const float*)d_in[0];
    const int*   adj   = (const int*)d_in[1];
    const float* W1    = (const float*)d_in[2];
    const float* b1    = (const float*)d_in[3];
    const float* a     = (const float*)d_in[4];
    const float* b_att = (const float*)d_in[5];
    float* out = (float*)d_out;

    char* ws = (char*)d_ws;
    unsigned long long* mask = (unsigned long long*)ws;        // 8 MB
    bf16* WhbF = (bf16*)(ws + (size_t)8 * 1024 * 1024);        // 2 MB
    float* E1 = (float*)(ws + (size_t)10 * 1024 * 1024);
    float* E2 = E1 + NODES;
    float* F1 = E2 + NODES;
    float* F2 = F1 + NODES;

    // bitpack: 131072 waves = 32768 blocks x 4 waves
    hipLaunchKernelGGL(gat_pack_r6, dim3(32768), dim3(256), 0, stream, adj, mask);

    hipLaunchKernelGGL(gat_prep_r6, dim3(NODES / 32), dim3(256), 0, stream,
                       x, W1, b1, a, b_att, WhbF, E1, E2, F1, F2);

    hipLaunchKernelGGL(gat_attn_r6, dim3(NODES / 32), dim3(1024), SMEM2_SIZE, stream,
                       (const unsigned int*)mask, WhbF, E1, E2, F1, F2, out);
}